// Round 7
// baseline (3965.550 us; speedup 1.0000x reference)
//
#include <hip/hip_runtime.h>
#include <math.h>

typedef unsigned long long u64;

// Problem constants
#define BB 32
#define TT 512
#define II 96

// d_out region offsets (floats)
#define O_HSEQ  1048576
#define O_AIN   26214400
#define O_ACM   51380224
#define O_ATTN  76546048

// ws layout (floats) — coop path: self-tagged mailboxes only
#define WS_VCF  0           /* tagged u64 [2][32][6][256]  = 98304 words  */
#define WS_QKT  196608      /* tagged u64 [2][32][192]     = 12288 words  */
#define WS_COOP_FLOATS 221184
// fallback staging (only when coop path unavailable)
#define WS_F_WEFF 0
#define WS_F_UT   49152
#define WS_F_WQT  73728
#define WS_F_WKT  98304
#define WS_F_FLOATS 122880

// lgkm-only barrier: orders LDS producer->consumer without draining vmcnt
#define LBAR() asm volatile("s_waitcnt lgkmcnt(0)\n\ts_barrier" ::: "memory")

__device__ __forceinline__ u64 sysld(const u64* p) {
  return __hip_atomic_load(p, __ATOMIC_RELAXED, __HIP_MEMORY_SCOPE_SYSTEM);
}
__device__ __forceinline__ void sysst(u64* p, u64 v) {
  __hip_atomic_store(p, v, __ATOMIC_RELAXED, __HIP_MEMORY_SCOPE_SYSTEM);
}
__device__ __forceinline__ u64 packtv(unsigned tag, float v) {
  return ((u64)tag << 32) | (u64)__float_as_uint(v);
}

// ---------------------------------------------------------------------------
// K1: parallel Ain_seq output (independent of the recurrence)
// ---------------------------------------------------------------------------
__global__ __launch_bounds__(256) void rim_pre(
    const float* __restrict__ x,
    const float* __restrict__ Wtask, const float* __restrict__ Wsens,
    float* __restrict__ Ain)
{
  __shared__ float xr[16][96];
  const int tid = threadIdx.x;
  const int rb0 = blockIdx.x * 16;
  for (int idx = tid; idx < 16 * 96; idx += 256) {
    int r = idx / 96, c = idx % 96;
    int rb = rb0 + r; int t = rb >> 5, b = rb & 31;
    xr[r][c] = x[(b * TT + t) * II + c];
  }
  __syncthreads();
  const int h = tid;
  float acc[16];

  for (int m = 0; m < 4; ++m) {
    const int cnt  = (m < 2) ? 32 : 64;
    const int xoff = (m < 2) ? 64 : 0;
    const float* W = (m < 2) ? (Wtask + m * 32 * 256) : (Wsens + (m - 2) * 64 * 256);
    #pragma unroll
    for (int r = 0; r < 16; ++r) acc[r] = 0.f;
    for (int i = 0; i < cnt; ++i) {
      float w = W[i * 256 + h];
      #pragma unroll
      for (int r = 0; r < 16; ++r) acc[r] += xr[r][xoff + i] * w;
    }
    #pragma unroll
    for (int r = 0; r < 16; ++r) {
      int rb = rb0 + r; int t = rb >> 5, b = rb & 31;
      Ain[((t * 32 + b) * 6 + m) * 256 + h] = acc[r];
    }
  }
  #pragma unroll
  for (int r = 0; r < 16; ++r) {
    int rb = rb0 + r; int t = rb >> 5, b = rb & 31;
    Ain[((t * 32 + b) * 6 + 4) * 256 + h] = 0.f;
    Ain[((t * 32 + b) * 6 + 5) * 256 + h] = 0.f;
  }
}

// ---------------------------------------------------------------------------
// K2: cooperative recurrence. 192 blocks = (m*32+b), 512 threads.
// Self-tagged 64-bit mailbox words (tag = t+1): no fences, no drains, no flags.
// 5 lgkm-only barriers/step. Self-staging init (no rim_weff dependency).
// ---------------------------------------------------------------------------
__global__ __launch_bounds__(512, 1) void rim_step(
    const float* __restrict__ x,
    const float* __restrict__ U, const float* __restrict__ Vr,
    const float* __restrict__ WV,
    const float* __restrict__ bip, const float* __restrict__ cbias,
    const float* __restrict__ WQ, const float* __restrict__ WK,
    const float* __restrict__ Wtask, const float* __restrict__ Wsens,
    const float* __restrict__ Wip,
    u64* __restrict__ VCF, u64* __restrict__ QKT,
    float* __restrict__ Hseq, float* __restrict__ Acm, float* __restrict__ attnO)
{
  __shared__ __align__(16) float Hl[256];
  __shared__ __align__(16) float Hin[256];
  __shared__ float biasl[256];
  __shared__ float Utl[16][257];    // +1 pad
  __shared__ float Vrl[16][257];
  __shared__ float WQtl[16][257];
  __shared__ float WKtl[16][257];
  __shared__ float Weffl[64][256];
  __shared__ float inpl[2][256];
  __shared__ float xl[2][96];
  __shared__ float Vcp1[256];
  __shared__ float tmpUr[16];
  __shared__ float attnl[40];
  __shared__ float qkl[192];
  __shared__ float wtmp[16][256];

  const int bid = blockIdx.x;
  const int m = bid >> 5;        // 0..5
  const int b = bid & 31;        // 0..31
  const int tid = threadIdx.x;
  const int g32 = tid >> 5, l32 = tid & 31;
  const int h_out = tid & 255, p = tid >> 8;
  const int g16 = tid >> 4, l16 = tid & 15;
  const int w64 = tid >> 6, lane = tid & 63;

  const int cnt  = (m < 2) ? 32 : 64;
  const int xoff = (m < 2) ? 64 : 0;

  // ---- init: transpose-stage U/WQ/WK, stage Vr, bias, H0 ----
  for (int i = tid; i < 4096; i += 512) {
    int r = i >> 8, c = i & 255;
    Utl [r][c] = U [m * 4096 + c * 16 + r];
    WQtl[r][c] = WQ[m * 4096 + c * 16 + r];
    WKtl[r][c] = WK[m * 4096 + c * 16 + r];
    Vrl [r][c] = Vr[m * 4096 + i];
  }
  if (tid < 256) {
    biasl[tid] = bip[m * 256 + tid] + cbias[m * 256 + tid];
    Hl[tid] = 0.f;
  }
  float xreg = 0.f;
  if (m < 4 && tid < 96) {
    xl[0][tid] = x[((size_t)b * TT + 0) * II + tid];
    xreg       = x[((size_t)b * TT + 1) * II + tid];
  }
  // W_V half-column: w[j] = WV[m][p*128+j][h_out]
  float w[128];
  #pragma unroll
  for (int j = 0; j < 128; ++j)
    w[j] = WV[((size_t)(m * 256 + p * 128 + j)) * 256 + h_out];

  // ---- init: Weff[m] = W_in[m] @ W_ip[m] computed in-block (m<4) ----
  if (m < 4) {
    const float* Win = (m < 2) ? (Wtask + m * 32 * 256) : (Wsens + (m - 2) * 64 * 256);
    const float* wip = Wip + m * 65536;
    const int hh = tid & 255, half8 = (tid >> 8) * 8;
    for (int c0 = 0; c0 < cnt; c0 += 16) {
      __syncthreads();
      for (int i = tid; i < 16 * 256; i += 512)
        wtmp[i >> 8][i & 255] = Win[(c0 + (i >> 8)) * 256 + (i & 255)];
      __syncthreads();
      float acc8[8];
      #pragma unroll
      for (int r = 0; r < 8; ++r) acc8[r] = 0.f;
      for (int j = 0; j < 256; ++j) {
        float wv = wip[j * 256 + hh];
        #pragma unroll
        for (int r = 0; r < 8; ++r) acc8[r] += wtmp[half8 + r][j] * wv;
      }
      #pragma unroll
      for (int r = 0; r < 8; ++r) Weffl[c0 + half8 + r][hh] = acc8[r];
    }
  }
  __syncthreads();
  // inp for t=0
  if (m < 4 && tid < 256) {
    float a = 0.f;
    for (int i = 0; i < cnt; ++i) a += xl[0][xoff + i] * Weffl[i][tid];
    inpl[0][tid] = a;
  }
  __syncthreads();

  for (int t = 0; t < TT; ++t) {
    const int buf = t & 1;
    const unsigned target = (unsigned)(t + 1);
    u64* vcb = VCF + (size_t)(buf * 32 + b) * 1536;  // [6][256]
    u64* qkb = QKT + (size_t)(buf * 32 + b) * 192;

    // x double-buffer: stage x_{t+1}, prefetch x_{t+2}
    if (m < 4 && tid < 96) {
      xl[(t + 1) & 1][tid] = xreg;
      xreg = (t + 2 < TT) ? x[((size_t)b * TT + t + 2) * II + tid] : 0.f;
    }

    // ---- P1: tmpUr[r] = sum_h Hl[h]*U[m][h][r] ----
    {
      float s = 0.f;
      const float* up = &Utl[g32][0];
      #pragma unroll
      for (int h = l32; h < 256; h += 32) s += Hl[h] * up[h];
      #pragma unroll
      for (int off = 16; off > 0; off >>= 1) s += __shfl_down(s, off, 32);
      if (l32 == 0) tmpUr[g32] = s;
    }
    LBAR();  // B1

    // ---- P2: Hin = tanh(inp + rec + bias) ----
    if (tid < 256) {
      float rec = 0.f;
      #pragma unroll
      for (int r = 0; r < 16; ++r) rec += tmpUr[r] * Vrl[r][tid];
      float inp = (m < 4) ? inpl[buf][tid] : 0.f;
      Hin[tid] = tanhf(inp + rec + biasl[tid]);
    }
    LBAR();  // B2

    // ---- P3: QK rows -> tagged publish (early); Vc half-dot ----
    {
      const int r = g16 & 15;
      const float* wp = (g16 < 16) ? &WQtl[r][0] : &WKtl[r][0];
      float s = 0.f;
      #pragma unroll
      for (int j = 0; j < 16; ++j) { int h = l16 + 16 * j; s += Hin[h] * wp[h]; }
      s += __shfl_down(s, 8, 16);
      s += __shfl_down(s, 4, 16);
      s += __shfl_down(s, 2, 16);
      s += __shfl_down(s, 1, 16);
      if (l16 == 0)
        sysst(&qkb[((g16 < 16) ? 0 : 96) + m * 16 + r], packtv(target, s));
    }
    float accVc = 0.f;
    {
      const float4* h4 = (const float4*)&Hin[p * 128];
      #pragma unroll
      for (int q = 0; q < 32; ++q) {
        float4 hv = h4[q];
        accVc += hv.x * w[4 * q] + hv.y * w[4 * q + 1]
               + hv.z * w[4 * q + 2] + hv.w * w[4 * q + 3];
      }
    }
    if (p == 1) Vcp1[h_out] = accVc;
    LBAR();  // B3

    float vC[6];
    if (tid < 256) {
      // publish own full Vc (tagged), then spin remote 5 (self-tagged data)
      float vown = accVc + Vcp1[tid];
      sysst(&vcb[m * 256 + tid], packtv(target, vown));
      u64 vw[6];
      #pragma unroll
      for (int mm = 0; mm < 6; ++mm)
        if (mm != m) vw[mm] = sysld(&vcb[mm * 256 + tid]);
      #pragma unroll
      for (int mm = 0; mm < 6; ++mm)
        if (mm != m)
          while ((unsigned)(vw[mm] >> 32) != target)
            vw[mm] = sysld(&vcb[mm * 256 + tid]);
      #pragma unroll
      for (int mm = 0; mm < 6; ++mm)
        vC[mm] = (mm == m) ? vown : __uint_as_float((unsigned)vw[mm]);
    } else if (w64 == 7) {
      // qk spins + in-wave softmax
      u64 a0 = sysld(&qkb[lane]);
      u64 a1 = sysld(&qkb[64 + lane]);
      u64 a2 = sysld(&qkb[128 + lane]);
      while ((unsigned)(a0 >> 32) != target) a0 = sysld(&qkb[lane]);
      while ((unsigned)(a1 >> 32) != target) a1 = sysld(&qkb[64 + lane]);
      while ((unsigned)(a2 >> 32) != target) a2 = sysld(&qkb[128 + lane]);
      qkl[lane]       = __uint_as_float((unsigned)a0);
      qkl[64 + lane]  = __uint_as_float((unsigned)a1);
      qkl[128 + lane] = __uint_as_float((unsigned)a2);
      asm volatile("s_waitcnt lgkmcnt(0)" ::: "memory");
      if (lane < 36) {
        const int mm6 = lane / 6, nn = lane % 6;
        float s = 0.f;
        #pragma unroll
        for (int k = 0; k < 16; ++k) s += qkl[mm6 * 16 + k] * qkl[96 + nn * 16 + k];
        s *= 0.25f;
        float mx = s;
        #pragma unroll
        for (int d = 1; d < 6; ++d)
          mx = fmaxf(mx, __shfl(s, mm6 * 6 + ((nn + d) % 6), 64));
        float e = __expf(s - mx);
        float sm = e;
        #pragma unroll
        for (int d = 1; d < 6; ++d)
          sm += __shfl(e, mm6 * 6 + ((nn + d) % 6), 64);
        float a = e / sm;
        attnl[lane] = a;
        if (m == 0) attnO[((size_t)t * 32 + b) * 36 + lane] = a;
      }
    } else {
      // waves 4-6: input projection for t+1 (off critical path)
      if (m < 4) {
        const int nb = (t + 1) & 1;
        for (int h = tid - 256; h < 256; h += 192) {
          float a = 0.f;
          for (int i = 0; i < cnt; ++i) a += xl[nb][xoff + i] * Weffl[i][h];
          inpl[nb][h] = a;
        }
      }
    }
    LBAR();  // B5 — attnl + inpl ready

    // ---- P7: A_comm + H_new ----
    if (tid < 256) {
      float ac = 0.f;
      #pragma unroll
      for (int mm = 0; mm < 6; ++mm) ac += attnl[mm * 6 + m] * vC[mm];
      float hn = Hin[tid] + ac;
      Hl[tid] = hn;
      size_t gi = (((size_t)t * 32 + b) * 6 + m) * 256 + tid;
      Hseq[gi] = hn;
      Acm[gi]  = ac;
    }
    LBAR();  // B7
  }
}

// ---------------------------------------------------------------------------
// K3: out[b,t,:] = concat(Hseq[t,b,4,:], Hseq[t,b,5,:]) @ W_out + b_out
// ---------------------------------------------------------------------------
__global__ __launch_bounds__(256) void rim_out(
    const float* __restrict__ Hseq, const float* __restrict__ Wout,
    const float* __restrict__ bout, float* __restrict__ out0)
{
  __shared__ float hrow[4][512];
  const int tid = threadIdx.x;
  const int row0 = blockIdx.x * 4;
  for (int i = tid; i < 4 * 512; i += 256) {
    int r = i >> 9, j = i & 511;
    int rb = row0 + r; int b = rb >> 9, t = rb & 511;
    hrow[r][j] = Hseq[((size_t)(t * 32 + b) * 6 + 4 + (j >> 8)) * 256 + (j & 255)];
  }
  __syncthreads();
  const int r = tid >> 6, o = tid & 63;
  const int rb = row0 + r;
  float s = bout[o];
  const float* hp = hrow[r];
  const float* wp = Wout + o;
  #pragma unroll 8
  for (int j = 0; j < 512; ++j) s += hp[j] * wp[(size_t)j * 64];
  out0[(size_t)rb * 64 + o] = s;
}

// ---------------------------------------------------------------------------
// Fallback path kernels (used only if ws is too small for the coop path)
// ---------------------------------------------------------------------------
__global__ __launch_bounds__(256) void rim_weff(
    const float* __restrict__ Wtask, const float* __restrict__ Wsens,
    const float* __restrict__ Wip,
    const float* __restrict__ U, const float* __restrict__ WQ, const float* __restrict__ WK,
    float* __restrict__ Weff, float* __restrict__ Ut, float* __restrict__ WQt, float* __restrict__ WKt)
{
  __shared__ float row[256];
  const int bidx = blockIdx.x;
  const int tid = threadIdx.x;
  if (bidx < 192) {
    int m, i;
    if (bidx < 32)       { m = 0; i = bidx; }
    else if (bidx < 64)  { m = 1; i = bidx - 32; }
    else if (bidx < 128) { m = 2; i = bidx - 64; }
    else                 { m = 3; i = bidx - 128; }
    row[tid] = (m < 2) ? Wtask[(m * 32 + i) * 256 + tid]
                       : Wsens[((m - 2) * 64 + i) * 256 + tid];
    __syncthreads();
    float acc = 0.f;
    const float* wip = Wip + m * 65536 + tid;
    #pragma unroll 8
    for (int j = 0; j < 256; ++j) acc += row[j] * wip[j * 256];
    const int base = (m == 0) ? 0 : (m == 1) ? 8192 : (m == 2) ? 16384 : 32768;
    Weff[base + i * 256 + tid] = acc;
  } else {
    const int p = bidx - 192;
    const int m = p >> 4, r = p & 15;
    Ut [(m * 16 + r) * 256 + tid] = U [m * 4096 + tid * 16 + r];
    WQt[(m * 16 + r) * 256 + tid] = WQ[m * 4096 + tid * 16 + r];
    WKt[(m * 16 + r) * 256 + tid] = WK[m * 4096 + tid * 16 + r];
  }
}

__global__ __launch_bounds__(512) void rim_loop(
    const float* __restrict__ x,
    const float* __restrict__ Vr, const float* __restrict__ WV,
    const float* __restrict__ Wout, const float* __restrict__ bout,
    const float* __restrict__ bip, const float* __restrict__ cbias,
    const float* __restrict__ Ut, const float* __restrict__ WQt, const float* __restrict__ WKt,
    const float* __restrict__ Weff,
    float* __restrict__ out0, float* __restrict__ Hseq,
    float* __restrict__ Acm, float* __restrict__ attnO)
{
  __shared__ float Hl[6][256];
  __shared__ float Hin[6][256];
  __shared__ float biasl[6][256];
  __shared__ float Vcp[2][6][256];
  __shared__ float tmpUr[6][16];
  __shared__ float Qc[6][16], Kc[6][16];
  __shared__ float attnl[36];
  __shared__ float pout[8][64];
  __shared__ float xl[96];
  __shared__ float inpl[4][256];

  const int b = blockIdx.x;
  const int tid = threadIdx.x;
  const int wid = tid >> 5, lane = tid & 31;

  for (int i = tid; i < 1536; i += 512) {
    int m = i >> 8, h = i & 255;
    biasl[m][h] = bip[i] + cbias[i];
    Hl[m][h] = 0.f;
  }
  __syncthreads();

  for (int t = 0; t < TT; ++t) {
    if (tid < 96) xl[tid] = x[(b * TT + t) * II + tid];
    __syncthreads();
    for (int mh = tid; mh < 1024; mh += 512) {
      int m = mh >> 8, h = mh & 255;
      const int base = (m == 0) ? 0 : (m == 1) ? 8192 : (m == 2) ? 16384 : 32768;
      const int cnt  = (m < 2) ? 32 : 64;
      const int xoff = (m < 2) ? 64 : 0;
      float a = 0.f;
      for (int i = 0; i < cnt; ++i) a += xl[xoff + i] * Weff[base + i * 256 + h];
      inpl[m][h] = a;
    }

    for (int pq = wid; pq < 96; pq += 16) {
      int m = pq >> 4, r = pq & 15;
      const float* up = Ut + (m * 16 + r) * 256;
      float s = 0.f;
      #pragma unroll
      for (int h = lane; h < 256; h += 32) s += Hl[m][h] * up[h];
      #pragma unroll
      for (int off = 16; off > 0; off >>= 1) s += __shfl_down(s, off, 32);
      if (lane == 0) tmpUr[m][r] = s;
    }
    __syncthreads();

    for (int mh = tid; mh < 1536; mh += 512) {
      int m = mh >> 8, h = mh & 255;
      float rec = 0.f;
      const float* vp = Vr + m * 4096 + h;
      #pragma unroll
      for (int r = 0; r < 16; ++r) rec += tmpUr[m][r] * vp[r * 256];
      float pre = (m < 4) ? inpl[m][h] : 0.f;
      Hin[m][h] = tanhf(pre + rec + biasl[m][h]);
    }
    __syncthreads();

    for (int pq = wid; pq < 192; pq += 16) {
      int q = pq % 96;
      int m = q >> 4, k = q & 15;
      const float* wp = ((pq < 96) ? WQt : WKt) + (m * 16 + k) * 256;
      float s = 0.f;
      #pragma unroll
      for (int h = lane; h < 256; h += 32) s += Hin[m][h] * wp[h];
      #pragma unroll
      for (int off = 16; off > 0; off >>= 1) s += __shfl_down(s, off, 32);
      if (lane == 0) { if (pq < 96) Qc[m][k] = s; else Kc[m][k] = s; }
    }

    {
      const int h_out = tid & 255, half = tid >> 8;
      for (int m = 0; m < 6; ++m) {
        const float* wv = WV + ((size_t)(m * 256 + half * 128)) * 256 + h_out;
        const float* hv = &Hin[m][half * 128];
        float s = 0.f;
        #pragma unroll 8
        for (int j = 0; j < 128; ++j) s += hv[j] * wv[(size_t)j * 256];
        Vcp[half][m][h_out] = s;
      }
    }
    __syncthreads();

    if (tid < 36) {
      int m = tid / 6, n = tid % 6;
      float s = 0.f;
      #pragma unroll
      for (int k = 0; k < 16; ++k) s += Qc[m][k] * Kc[n][k];
      attnl[tid] = s * 0.25f;
    }
    __syncthreads();
    if (tid < 6) {
      int m = tid;
      float mx = -1e30f;
      #pragma unroll
      for (int n = 0; n < 6; ++n) mx = fmaxf(mx, attnl[m * 6 + n]);
      float e[6], sm = 0.f;
      #pragma unroll
      for (int n = 0; n < 6; ++n) { e[n] = expf(attnl[m * 6 + n] - mx); sm += e[n]; }
      float inv = 1.f / sm;
      #pragma unroll
      for (int n = 0; n < 6; ++n) attnl[m * 6 + n] = e[n] * inv;
    }
    __syncthreads();
    if (tid < 36) attnO[(size_t)(t * 32 + b) * 36 + tid] = attnl[tid];

    for (int mh = tid; mh < 1536; mh += 512) {
      int n = mh >> 8, h = mh & 255;
      float ac = 0.f;
      #pragma unroll
      for (int m = 0; m < 6; ++m)
        ac += attnl[m * 6 + n] * (Vcp[0][m][h] + Vcp[1][m][h]);
      float hn = Hin[n][h] + ac;
      Hl[n][h] = hn;
      size_t gi = ((size_t)(t * 32 + b) * 6 + n) * 256 + h;
      Hseq[gi] = hn;
      Acm[gi]  = ac;
    }
    __syncthreads();

    {
      const int o = tid & 63, js = tid >> 6;
      const float* hp = &Hl[4][0];
      const float* wp = Wout + (size_t)(js * 64) * 64 + o;
      float s = 0.f;
      #pragma unroll 8
      for (int jj = 0; jj < 64; ++jj) s += hp[js * 64 + jj] * wp[(size_t)jj * 64];
      pout[js][o] = s;
    }
    __syncthreads();
    if (tid < 64) {
      float s = bout[tid];
      #pragma unroll
      for (int js = 0; js < 8; ++js) s += pout[js][tid];
      out0[(size_t)(b * TT + t) * 64 + tid] = s;
    }
  }
}

// ---------------------------------------------------------------------------
extern "C" void kernel_launch(void* const* d_in, const int* in_sizes, int n_in,
                              void* d_out, int out_size, void* d_ws, size_t ws_size,
                              hipStream_t stream) {
  const float* x    = (const float*)d_in[0];
  const float* W_ip = (const float*)d_in[1];
  const float* b_ip = (const float*)d_in[2];
  const float* U    = (const float*)d_in[3];
  const float* Vr   = (const float*)d_in[4];
  const float* cb   = (const float*)d_in[5];
  const float* Wt   = (const float*)d_in[6];
  const float* Wsn  = (const float*)d_in[7];
  const float* WQ   = (const float*)d_in[8];
  const float* WK   = (const float*)d_in[9];
  const float* WV   = (const float*)d_in[10];
  const float* Wo   = (const float*)d_in[11];
  const float* bo   = (const float*)d_in[12];

  float* out  = (float*)d_out;
  float* Hseq = out + O_HSEQ;
  float* Ain  = out + O_AIN;
  float* Acm  = out + O_ACM;
  float* attn = out + O_ATTN;

  float* ws = (float*)d_ws;

  hipLaunchKernelGGL(rim_pre, dim3(1024), dim3(256), 0, stream,
                     x, Wt, Wsn, Ain);

  if (ws_size >= (size_t)WS_COOP_FLOATS * sizeof(float)) {
    u64* VCF = (u64*)(ws + WS_VCF);
    u64* QKT = (u64*)(ws + WS_QKT);
    // clear mailbox tags (in-graph, per launch: stale/garbage tags never match)
    hipMemsetAsync((void*)ws, 0, (size_t)WS_COOP_FLOATS * sizeof(float), stream);

    void* args[] = { (void*)&x, (void*)&U, (void*)&Vr, (void*)&WV,
                     (void*)&b_ip, (void*)&cb, (void*)&WQ, (void*)&WK,
                     (void*)&Wt, (void*)&Wsn, (void*)&W_ip,
                     (void*)&VCF, (void*)&QKT,
                     (void*)&Hseq, (void*)&Acm, (void*)&attn };
    hipLaunchCooperativeKernel((void*)rim_step, dim3(192), dim3(512), args, 0, stream);

    hipLaunchKernelGGL(rim_out, dim3(4096), dim3(256), 0, stream,
                       Hseq, Wo, bo, out);
  } else {
    float* Weff = ws + WS_F_WEFF;
    float* Ut   = ws + WS_F_UT;
    float* WQt  = ws + WS_F_WQT;
    float* WKt  = ws + WS_F_WKT;
    hipLaunchKernelGGL(rim_weff, dim3(288), dim3(256), 0, stream,
                       Wt, Wsn, W_ip, U, WQ, WK, Weff, Ut, WQt, WKt);
    hipLaunchKernelGGL(rim_loop, dim3(32), dim3(512), 0, stream,
                       x, Vr, WV, Wo, bo, b_ip, cb, Ut, WQt, WKt, Weff,
                       out, Hseq, Acm, attn);
  }
}